// Round 5
// baseline (216.525 us; speedup 1.0000x reference)
//
#include <hip/hip_runtime.h>
#include <stdint.h>

typedef short v8s  __attribute__((ext_vector_type(8)));
typedef float v16f __attribute__((ext_vector_type(16)));

#define KS    7
#define KPTS  9
#define OCH   128
#define CCH   128
#define NB    32
#define HW    56
#define PAD   3

#define HBLK  8
#define ROWS  14            // HBLK + 6
#define WP    72
#define CCK   32
#define NCC   4
#define HP    62
#define ROWB  (WP*CCK*2)    // 4608 B per padded x_t row
#define SMEM_B 65536        // 64 staging lines of 1024 B (63 real + 1 pad)

__device__ __forceinline__ unsigned short f2bf(float f) {
  unsigned int u = __builtin_bit_cast(unsigned int, f);
  u += 0x7fffu + ((u >> 16) & 1u);
  return (unsigned short)(u >> 16);
}

__device__ __forceinline__ void gl_lds16(const void* g, void* l) {
  __builtin_amdgcn_global_load_lds(
      (const __attribute__((address_space(1))) unsigned int*)g,
      (__attribute__((address_space(3))) unsigned int*)l, 16, 0, 0);
}

// Kernel construction: block = c (128), thread = o (128). Private 49-float row
// in LDS -> no atomics. Output kb [cc][tap][chunk8][lane64][8c] bf16 where
// chunk = ks*4 + mt; lane l holds (o = mt*32 + (l&31), c = ks*16 + (l>>5)*8 + j)
// -> each A-fragment load in conv is one lane-linear 1 KB global_load_dwordx4.
__global__ __launch_bounds__(128) void build_kern(
    const float* __restrict__ wgt, const float* __restrict__ P,
    unsigned short* __restrict__ kb) {
  __shared__ float sm[OCH*49];
  const int c = blockIdx.x, o = threadIdx.x;
  float* mine = &sm[o*49];
  #pragma unroll
  for (int j = 0; j < 49; ++j) mine[j] = 0.f;
  for (int k = 0; k < KPTS; ++k) {
    const float ph = fminf(fmaxf(P[c*KPTS + k], -3.f), 3.f) + 3.f;
    const float pw = fminf(fmaxf(P[CCH*KPTS + c*KPTS + k], -3.f), 3.f) + 3.f;
    const int ih = (int)floorf(ph), iw = (int)floorf(pw);
    const float rh = ph - (float)ih, rw = pw - (float)iw;
    const float wt = wgt[(o*CCH + c)*KPTS + k];
    mine[ih*KS + iw] += wt*(1.f-rh)*(1.f-rw);
    if (iw+1 < KS) mine[ih*KS + iw+1] += wt*(1.f-rh)*rw;
    if (ih+1 < KS) mine[(ih+1)*KS + iw] += wt*rh*(1.f-rw);
    if (ih+1 < KS && iw+1 < KS) mine[(ih+1)*KS + iw+1] += wt*rh*rw;
  }
  const int cc = c >> 5, c32 = c & 31;
  const int ks = c32 >> 4, g = (c32 >> 3) & 1, j = c & 7;
  const int mt = o >> 5, l5 = o & 31;
  const size_t base = ((size_t)cc*49*8 + ks*4 + mt)*512 + (g*32 + l5)*8 + j;
  for (int tap = 0; tap < 49; ++tap)
    kb[base + (size_t)tap*4096] = f2bf(mine[tap]);
}

// x [n][c][h][w] f32 -> x_t [n][cc][h'][w'][c32] bf16, pads baked as zeros,
// B-swizzle baked: data chunk s stored at phys chunk s ^ ((w'>>1)&3).
__global__ __launch_bounds__(256) void xpose(const float* __restrict__ x,
                                             unsigned short* __restrict__ xt) {
  __shared__ unsigned short lb[CCK][HW + 2];
  const int hp = blockIdx.x;
  const int cc = blockIdx.y;
  const int n  = blockIdx.z;
  const int t  = threadIdx.x;
  const int h  = hp - PAD;
  const bool valid = (unsigned)h < (unsigned)HW;
  if (valid) {
    const float* xb = x + ((size_t)(n*CCH + cc*CCK)*HW + h)*HW;
    #pragma unroll
    for (int k = 0; k < 7; ++k) {
      const int j = k*256 + t;
      const int c = j / HW, w = j % HW;
      lb[c][w] = f2bf(xb[(size_t)c*HW*HW + w]);
    }
  }
  __syncthreads();
  unsigned short* orow = xt + (size_t)((n*NCC + cc)*HP + hp)*(WP*CCK);
  for (int q = t; q < WP*4; q += 256) {
    const int wq = q >> 2, pc = q & 3;
    const int s  = pc ^ ((wq >> 1) & 3);
    v8s v = (v8s){0,0,0,0,0,0,0,0};
    const int w = wq - PAD;
    if (valid && (unsigned)w < (unsigned)HW) {
      #pragma unroll
      for (int jj = 0; jj < 8; ++jj) v[jj] = (short)lb[s*8 + jj][w];
    }
    *(v8s*)&orow[wq*CCK + pc*8] = v;
  }
}

// One tap: prefetch A(T+1) global->NXT regs, read B frags from xs, 16x 32x32x16
// MFMA with CUR regs. No barriers -- waves free-run within a cc pass.
#define TAP_BODY(T, CUR, NXT, PF)                                             \
  {                                                                           \
    const int kh = (T)/7, kw = (T) - kh*7;                                    \
    if (PF) {                                                                 \
      const unsigned short* kn = kt + (size_t)((T)+1)*4096;                   \
      _Pragma("unroll")                                                       \
      for (int f = 0; f < 8; ++f)                                             \
        NXT[f] = *(const v8s*)&kn[f*512 + lane*8];                            \
    }                                                                         \
    const int r = wv + kh;                                                    \
    v8s bf[2][2];                                                             \
    _Pragma("unroll")                                                         \
    for (int nt = 0; nt < 2; ++nt) {                                          \
      const int w = nt*32 + l5 + kw;                                          \
      const int xw = (w >> 1) & 3;                                            \
      _Pragma("unroll")                                                       \
      for (int ks = 0; ks < 2; ++ks) {                                        \
        const int phys = (ks*2 + g) ^ xw;                                     \
        bf[nt][ks] = *(const v8s*)&xs[(r*WP + w)*CCK + phys*8];               \
      }                                                                       \
    }                                                                         \
    __builtin_amdgcn_s_setprio(1);                                            \
    _Pragma("unroll")                                                         \
    for (int ks = 0; ks < 2; ++ks)                                            \
      _Pragma("unroll")                                                       \
      for (int mt = 0; mt < 4; ++mt)                                          \
        _Pragma("unroll")                                                     \
        for (int nt = 0; nt < 2; ++nt)                                        \
          acc[mt][nt] = __builtin_amdgcn_mfma_f32_32x32x16_bf16(              \
              CUR[ks*4 + mt], bf[nt][ks], acc[mt][nt], 0, 0, 0);              \
    __builtin_amdgcn_s_setprio(0);                                            \
  }

// Conv: grid 32 x 7 = 224 blocks (1/CU). 512 thr = 8 waves, wave = one h-row,
// per-wave tile M=128(o) x N=64(w), 32x32x16 MFMA. A direct from global (L1-
// resident 1.6 MB kb), B from 64 KB xs LDS. Barriers only at cc boundaries.
__global__ __launch_bounds__(512, 2) void dcls_conv(
    const unsigned short* __restrict__ xt, const unsigned short* __restrict__ kb,
    const float* __restrict__ bias, float* __restrict__ out)
{
  extern __shared__ char smem[];
  unsigned short* xs = (unsigned short*)smem;   // [ROWS][WP][CCK] (+pad line)

  const int n   = blockIdx.x;
  const int hb  = blockIdx.y;
  const int tid = threadIdx.x;
  const int lane = tid & 63;
  const int wv   = tid >> 6;
  const int l5   = lane & 31;
  const int g    = lane >> 5;

  v16f acc[4][2];
  {
    v16f z;
    #pragma unroll
    for (int i = 0; i < 16; ++i) z[i] = 0.f;
    #pragma unroll
    for (int m = 0; m < 4; ++m)
      #pragma unroll
      for (int t = 0; t < 2; ++t)
        acc[m][t] = z;
  }

  v8s A0[8], A1[8];

  for (int cc = 0; cc < NCC; ++cc) {
    __syncthreads();   // all waves done reading xs of previous cc
    // ---- stage xs: 64 linear KB lines via global_load_lds ----
    const char* src = (const char*)xt + (size_t)((n*NCC + cc)*HP + hb*HBLK)*ROWB;
    #pragma unroll
    for (int q = 0; q < 8; ++q)
      gl_lds16(src + (wv*8 + q)*1024 + lane*16, (char*)xs + (wv*8 + q)*1024);
    // ---- preload A(0) into regs (global, L1/L2) ----
    const unsigned short* kt = kb + (size_t)cc*49*4096;
    #pragma unroll
    for (int f = 0; f < 8; ++f)
      A0[f] = *(const v8s*)&kt[f*512 + lane*8];
    __syncthreads();   // full drain: xs resident and visible

    int t = 0;
    #pragma unroll 1
    for (int p = 0; p < 24; ++p) {
      TAP_BODY(t,     A0, A1, true)
      TAP_BODY(t + 1, A1, A0, true)
      t += 2;
    }
    TAP_BODY(48, A0, A1, false)
  }

  // ---- epilogue: C/D 32x32: col(w) = lane&31, row(o) = (r&3)+8*(r>>2)+4*g ----
  const int h = hb*HBLK + wv;
  #pragma unroll
  for (int mt = 0; mt < 4; ++mt) {
    #pragma unroll
    for (int rr = 0; rr < 16; ++rr) {
      const int o = mt*32 + (rr & 3) + 8*(rr >> 2) + 4*g;
      const int w = l5;   // nt=0
      float v0 = acc[mt][0][rr] + bias[o];
      out[((size_t)(n*OCH + o)*HW + h)*HW + w] = v0;
      if (l5 < 24) {
        float v1 = acc[mt][1][rr] + bias[o];
        out[((size_t)(n*OCH + o)*HW + h)*HW + 32 + l5] = v1;
      }
    }
  }
}

extern "C" void kernel_launch(void* const* d_in, const int* in_sizes, int n_in,
                              void* d_out, int out_size, void* d_ws, size_t ws_size,
                              hipStream_t stream) {
  const float* x    = (const float*)d_in[0];
  const float* wgt  = (const float*)d_in[1];
  const float* P    = (const float*)d_in[2];
  const float* bias = (const float*)d_in[3];
  float* out = (float*)d_out;

  unsigned short* kb = (unsigned short*)d_ws;                       // 1.6 MB
  unsigned short* xt = (unsigned short*)((char*)d_ws + (2u<<20));   // 36.6 MB (+4KB pad slack)

  hipFuncSetAttribute((const void*)dcls_conv,
                      hipFuncAttributeMaxDynamicSharedMemorySize, SMEM_B);

  build_kern<<<CCH, OCH, 0, stream>>>(wgt, P, kb);
  xpose<<<dim3(HP, NCC, NB), 256, 0, stream>>>(x, xt);
  dcls_conv<<<dim3(NB, KS), 512, SMEM_B, stream>>>(xt, kb, bias, out);
}

// Round 6
// 179.542 us; speedup vs baseline: 1.2060x; 1.2060x over previous
//
#include <hip/hip_runtime.h>
#include <stdint.h>

typedef short v8s __attribute__((ext_vector_type(8)));
typedef float v4f __attribute__((ext_vector_type(4)));

#define KS    7
#define KPTS  9
#define OCH   128
#define CCH   128
#define NB    32
#define HW    56
#define PAD   3

#define HBLK  8
#define ROWS  14            // HBLK + 6
#define WP    72
#define CCK   32
#define NCC   4
#define HP    62
#define ROWB  (WP*CCK*2)        // 4608 B per padded x_t row
#define XS_B  (ROWS*WP*CCK*2)   // 64512 B = 63 KB-lines
#define AB_B  (4*OCH*CCK*2)     // 32768 B (ring of 4 A-buffers)
#define SMEM_B (XS_B + AB_B)    // 97280 B -> 1 block/CU

__device__ __forceinline__ unsigned short f2bf(float f) {
  unsigned int u = __builtin_bit_cast(unsigned int, f);
  u += 0x7fffu + ((u >> 16) & 1u);
  return (unsigned short)(u >> 16);
}

__device__ __forceinline__ void gl_lds16(const void* g, void* l) {
  __builtin_amdgcn_global_load_lds(
      (const __attribute__((address_space(1))) unsigned int*)g,
      (__attribute__((address_space(3))) unsigned int*)l, 16, 0, 0);
}

// Kernel construction: block = c (128), thread = o (128). Private 49-float row
// in LDS -> no atomics. kb [cc][tap][o][c32] bf16, A-swizzle baked
// (chunk ^ ((o>>1)&3)) -- the R4 layout (proven conflict-free in conv).
__global__ __launch_bounds__(128) void build_kern(
    const float* __restrict__ wgt, const float* __restrict__ P,
    unsigned short* __restrict__ kb) {
  __shared__ float sm[OCH*49];
  const int c = blockIdx.x, o = threadIdx.x;
  float* mine = &sm[o*49];
  #pragma unroll
  for (int j = 0; j < 49; ++j) mine[j] = 0.f;
  for (int k = 0; k < KPTS; ++k) {
    const float ph = fminf(fmaxf(P[c*KPTS + k], -3.f), 3.f) + 3.f;
    const float pw = fminf(fmaxf(P[CCH*KPTS + c*KPTS + k], -3.f), 3.f) + 3.f;
    const int ih = (int)floorf(ph), iw = (int)floorf(pw);
    const float rh = ph - (float)ih, rw = pw - (float)iw;
    const float wt = wgt[(o*CCH + c)*KPTS + k];
    mine[ih*KS + iw] += wt*(1.f-rh)*(1.f-rw);
    if (iw+1 < KS) mine[ih*KS + iw+1] += wt*(1.f-rh)*rw;
    if (ih+1 < KS) mine[(ih+1)*KS + iw] += wt*rh*(1.f-rw);
    if (ih+1 < KS && iw+1 < KS) mine[(ih+1)*KS + iw+1] += wt*rh*rw;
  }
  const int cc = c >> 5, sc = (c >> 3) & 3, cl = c & 7;
  const int pc = sc ^ ((o >> 1) & 3);
  for (int tap = 0; tap < 49; ++tap)
    kb[(((size_t)(cc*49 + tap)*OCH + o)*CCK) + pc*8 + cl] = f2bf(mine[tap]);
}

// x [n][c][h][w] f32 -> x_t [n][cc][h'][w'][c32] bf16, pads baked as zeros,
// B-swizzle baked: data chunk s stored at phys chunk s ^ ((w'>>1)&3).
__global__ __launch_bounds__(256) void xpose(const float* __restrict__ x,
                                             unsigned short* __restrict__ xt) {
  __shared__ unsigned short lb[CCK][HW + 2];
  const int hp = blockIdx.x;
  const int cc = blockIdx.y;
  const int n  = blockIdx.z;
  const int t  = threadIdx.x;
  const int h  = hp - PAD;
  const bool valid = (unsigned)h < (unsigned)HW;
  if (valid) {
    const float* xb = x + ((size_t)(n*CCH + cc*CCK)*HW + h)*HW;
    #pragma unroll
    for (int k = 0; k < 7; ++k) {
      const int j = k*256 + t;
      const int c = j / HW, w = j % HW;
      lb[c][w] = f2bf(xb[(size_t)c*HW*HW + w]);
    }
  }
  __syncthreads();
  unsigned short* orow = xt + (size_t)((n*NCC + cc)*HP + hp)*(WP*CCK);
  for (int q = t; q < WP*4; q += 256) {
    const int wq = q >> 2, pc = q & 3;
    const int s  = pc ^ ((wq >> 1) & 3);
    v8s v = (v8s){0,0,0,0,0,0,0,0};
    const int w = wq - PAD;
    if (valid && (unsigned)w < (unsigned)HW) {
      #pragma unroll
      for (int jj = 0; jj < 8; ++jj) v[jj] = (short)lb[s*8 + jj][w];
    }
    *(v8s*)&orow[wq*CCK + pc*8] = v;
  }
}

// One tap's compute: read A frags from ring[T&3], B frags from xs, 32 MFMAs.
#define TAP_COMPUTE(T)                                                        \
  {                                                                           \
    const int kh = (T)/7, kw = (T) - kh*7;                                    \
    const int r = wv + kh;                                                    \
    const unsigned short* ap = ab + (size_t)((T) & 3)*(OCH*CCK);              \
    v8s a[8], b[4];                                                           \
    _Pragma("unroll")                                                         \
    for (int mt = 0; mt < 8; ++mt)                                            \
      a[mt] = *(const v8s*)&ap[(mt*16 + col)*CCK + swA];                      \
    _Pragma("unroll")                                                         \
    for (int nt = 0; nt < 4; ++nt) {                                          \
      const int wp = nt*16 + col + kw;                                        \
      b[nt] = *(const v8s*)&xs[(r*WP + wp)*CCK +                              \
                               ((kgrp ^ ((wp >> 1) & 3)) << 3)];              \
    }                                                                         \
    __builtin_amdgcn_s_setprio(1);                                            \
    _Pragma("unroll")                                                         \
    for (int nt = 0; nt < 4; ++nt)                                            \
      _Pragma("unroll")                                                       \
      for (int mt = 0; mt < 8; ++mt)                                          \
        acc[mt][nt] = __builtin_amdgcn_mfma_f32_16x16x32_bf16(                \
            a[mt], b[nt], acc[mt][nt], 0, 0, 0);                              \
    __builtin_amdgcn_s_setprio(0);                                            \
  }

// Conv: grid 32 x 7 = 224 blocks (1/CU, uniform). 512 thr = 8 waves, wave =
// one h-row, per-wave tile M=128(o) x N=64(w), 16x16x32 MFMA.
// A ring-buffered in LDS with counted vmcnt: s_waitcnt vmcnt(2) + raw
// s_barrier per tap -- prefetches stay in flight across barriers (T4).
__global__ __launch_bounds__(512, 2) void dcls_conv(
    const unsigned short* __restrict__ xt, const unsigned short* __restrict__ kb,
    const float* __restrict__ bias, float* __restrict__ out)
{
  extern __shared__ char smem[];
  unsigned short* xs = (unsigned short*)smem;            // [ROWS][WP][CCK]
  unsigned short* ab = (unsigned short*)(smem + XS_B);   // ring of 4 [OCH][CCK]

  const int n   = blockIdx.x;
  const int hb  = blockIdx.y;
  const int tid = threadIdx.x;
  const int lane = tid & 63;
  const int wv   = tid >> 6;        // 0..7 = h-row within block
  const int col  = lane & 15;
  const int kgrp = lane >> 4;
  const int swA  = (kgrp ^ ((col >> 1) & 3)) << 3;

  v4f acc[8][4];
  #pragma unroll
  for (int m = 0; m < 8; ++m)
    #pragma unroll
    for (int t = 0; t < 4; ++t)
      acc[m][t] = (v4f){0.f,0.f,0.f,0.f};

  for (int cc = 0; cc < NCC; ++cc) {
    __syncthreads();   // all waves done reading previous cc's xs/ring
    // ---- stage xs: 63 linear KB-lines via global_load_lds ----
    const char* src = (const char*)xt + (size_t)((n*NCC + cc)*HP + hb*HBLK)*ROWB;
    for (int i = wv; i < 63; i += 8)
      gl_lds16(src + i*1024 + lane*16, (char*)xs + i*1024);
    // ---- stage A(0), A(1): wave w copies line w of each 8 KB tile ----
    const char* ks = (const char*)kb + (size_t)cc*49*8192;
    gl_lds16(ks + wv*1024 + lane*16, (char*)ab + wv*1024 + lane*16);
    gl_lds16(ks + 8192 + wv*1024 + lane*16, (char*)ab + 8192 + wv*1024 + lane*16);
    asm volatile("s_waitcnt vmcnt(0)" ::: "memory");
    __builtin_amdgcn_s_barrier();

    #pragma unroll 1
    for (int T = 0; T < 47; ++T) {
      // prefetch A(T+2) into ring[(T+2)&3]; stays in flight across barrier
      gl_lds16(ks + (size_t)(T + 2)*8192 + wv*1024 + lane*16,
               (char*)ab + (size_t)((T + 2) & 3)*8192 + wv*1024 + lane*16);
      asm volatile("s_waitcnt vmcnt(2)" ::: "memory");  // A(T) done; A(T+1),A(T+2) in flight
      __builtin_amdgcn_s_barrier();
      TAP_COMPUTE(T)
    }
    asm volatile("s_waitcnt vmcnt(1)" ::: "memory");    // A(47) done
    __builtin_amdgcn_s_barrier();
    TAP_COMPUTE(47)
    asm volatile("s_waitcnt vmcnt(0)" ::: "memory");    // A(48) done
    __builtin_amdgcn_s_barrier();
    TAP_COMPUTE(48)
  }

  // ---- epilogue: D row=(lane>>4)*4+reg, col=lane&15 ----
  const int h = hb*HBLK + wv;
  #pragma unroll
  for (int mt = 0; mt < 8; ++mt) {
    #pragma unroll
    for (int rr = 0; rr < 4; ++rr) {
      const int o = mt*16 + (lane >> 4)*4 + rr;
      const float bs = bias[o];
      #pragma unroll
      for (int nt = 0; nt < 4; ++nt) {
        const int w = nt*16 + col;
        if (w < HW)
          out[((size_t)(n*OCH + o)*HW + h)*HW + w] = acc[mt][nt][rr] + bs;
      }
    }
  }
}

extern "C" void kernel_launch(void* const* d_in, const int* in_sizes, int n_in,
                              void* d_out, int out_size, void* d_ws, size_t ws_size,
                              hipStream_t stream) {
  const float* x    = (const float*)d_in[0];
  const float* wgt  = (const float*)d_in[1];
  const float* P    = (const float*)d_in[2];
  const float* bias = (const float*)d_in[3];
  float* out = (float*)d_out;

  unsigned short* kb = (unsigned short*)d_ws;                       // 1.6 MB
  unsigned short* xt = (unsigned short*)((char*)d_ws + (2u<<20));   // 36.6 MB

  hipFuncSetAttribute((const void*)dcls_conv,
                      hipFuncAttributeMaxDynamicSharedMemorySize, SMEM_B);

  build_kern<<<CCH, OCH, 0, stream>>>(wgt, P, kb);
  xpose<<<dim3(HP, NCC, NB), 256, 0, stream>>>(x, xt);
  dcls_conv<<<dim3(NB, KS), 512, SMEM_B, stream>>>(xt, kb, bias, out);
}

// Round 7
// 163.286 us; speedup vs baseline: 1.3260x; 1.0996x over previous
//
#include <hip/hip_runtime.h>
#include <stdint.h>

typedef short v8s __attribute__((ext_vector_type(8)));
typedef float v4f __attribute__((ext_vector_type(4)));

#define KS    7
#define KPTS  9
#define OCH   128
#define CCH   128
#define NB    32
#define HW    56
#define PAD   3

#define HBLK  8
#define ROWS  14            // HBLK + 6
#define WP    72
#define CCK   32
#define NCC   4
#define HP    62
#define ROWB  (WP*CCK*2)        // 4608 B per padded x_t row
#define XS_B  (ROWS*WP*CCK*2)   // 64512 B = 63 KB-lines
#define AB_B  (8*OCH*CCK*2)     // 65536 B (ring of 8 A-slots)
#define SMEM_B (XS_B + AB_B)    // 130048 B -> 1 block/CU

__device__ __forceinline__ unsigned short f2bf(float f) {
  unsigned int u = __builtin_bit_cast(unsigned int, f);
  u += 0x7fffu + ((u >> 16) & 1u);
  return (unsigned short)(u >> 16);
}

__device__ __forceinline__ void gl_lds16(const void* g, void* l) {
  __builtin_amdgcn_global_load_lds(
      (const __attribute__((address_space(1))) unsigned int*)g,
      (__attribute__((address_space(3))) unsigned int*)l, 16, 0, 0);
}

// Kernel construction: block = c (128), thread = o (128). Private 49-float row
// in LDS -> no atomics. kb [cc][tap][o][c32] bf16, A-swizzle baked
// (chunk ^ ((o>>1)&3)).
__global__ __launch_bounds__(128) void build_kern(
    const float* __restrict__ wgt, const float* __restrict__ P,
    unsigned short* __restrict__ kb) {
  __shared__ float sm[OCH*49];
  const int c = blockIdx.x, o = threadIdx.x;
  float* mine = &sm[o*49];
  #pragma unroll
  for (int j = 0; j < 49; ++j) mine[j] = 0.f;
  for (int k = 0; k < KPTS; ++k) {
    const float ph = fminf(fmaxf(P[c*KPTS + k], -3.f), 3.f) + 3.f;
    const float pw = fminf(fmaxf(P[CCH*KPTS + c*KPTS + k], -3.f), 3.f) + 3.f;
    const int ih = (int)floorf(ph), iw = (int)floorf(pw);
    const float rh = ph - (float)ih, rw = pw - (float)iw;
    const float wt = wgt[(o*CCH + c)*KPTS + k];
    mine[ih*KS + iw] += wt*(1.f-rh)*(1.f-rw);
    if (iw+1 < KS) mine[ih*KS + iw+1] += wt*(1.f-rh)*rw;
    if (ih+1 < KS) mine[(ih+1)*KS + iw] += wt*rh*(1.f-rw);
    if (ih+1 < KS && iw+1 < KS) mine[(ih+1)*KS + iw+1] += wt*rh*rw;
  }
  const int cc = c >> 5, sc = (c >> 3) & 3, cl = c & 7;
  const int pc = sc ^ ((o >> 1) & 3);
  for (int tap = 0; tap < 49; ++tap)
    kb[(((size_t)(cc*49 + tap)*OCH + o)*CCK) + pc*8 + cl] = f2bf(mine[tap]);
}

// x [n][c][h][w] f32 -> x_t [n][cc][h'][w'][c32] bf16, pads baked as zeros,
// B-swizzle baked: data chunk s stored at phys chunk s ^ ((w'>>1)&3).
__global__ __launch_bounds__(256) void xpose(const float* __restrict__ x,
                                             unsigned short* __restrict__ xt) {
  __shared__ unsigned short lb[CCK][HW + 2];
  const int hp = blockIdx.x;
  const int cc = blockIdx.y;
  const int n  = blockIdx.z;
  const int t  = threadIdx.x;
  const int h  = hp - PAD;
  const bool valid = (unsigned)h < (unsigned)HW;
  if (valid) {
    const float* xb = x + ((size_t)(n*CCH + cc*CCK)*HW + h)*HW;
    #pragma unroll
    for (int k = 0; k < 7; ++k) {
      const int j = k*256 + t;
      const int c = j / HW, w = j % HW;
      lb[c][w] = f2bf(xb[(size_t)c*HW*HW + w]);
    }
  }
  __syncthreads();
  unsigned short* orow = xt + (size_t)((n*NCC + cc)*HP + hp)*(WP*CCK);
  for (int q = t; q < WP*4; q += 256) {
    const int wq = q >> 2, pc = q & 3;
    const int s  = pc ^ ((wq >> 1) & 3);
    v8s v = (v8s){0,0,0,0,0,0,0,0};
    const int w = wq - PAD;
    if (valid && (unsigned)w < (unsigned)HW) {
      #pragma unroll
      for (int jj = 0; jj < 8; ++jj) v[jj] = (short)lb[s*8 + jj][w];
    }
    *(v8s*)&orow[wq*CCK + pc*8] = v;
  }
}

// One tap's compute: read A frags from ring slot T&7, B frags from xs, 32 MFMAs.
#define TAP_COMPUTE(T)                                                        \
  {                                                                           \
    const int kh = (T)/7, kw = (T) - kh*7;                                    \
    const int r = wv + kh;                                                    \
    const unsigned short* ap = ab + (size_t)((T) & 7)*(OCH*CCK);              \
    v8s a[8], b[4];                                                           \
    _Pragma("unroll")                                                         \
    for (int mt = 0; mt < 8; ++mt)                                            \
      a[mt] = *(const v8s*)&ap[(mt*16 + col)*CCK + swA];                      \
    _Pragma("unroll")                                                         \
    for (int nt = 0; nt < 4; ++nt) {                                          \
      const int wp = nt*16 + col + kw;                                        \
      b[nt] = *(const v8s*)&xs[(r*WP + wp)*CCK +                              \
                               ((kgrp ^ ((wp >> 1) & 3)) << 3)];              \
    }                                                                         \
    __builtin_amdgcn_s_setprio(1);                                            \
    _Pragma("unroll")                                                         \
    for (int nt = 0; nt < 4; ++nt)                                            \
      _Pragma("unroll")                                                       \
      for (int mt = 0; mt < 8; ++mt)                                          \
        acc[mt][nt] = __builtin_amdgcn_mfma_f32_16x16x32_bf16(                \
            a[mt], b[nt], acc[mt][nt], 0, 0, 0);                              \
    __builtin_amdgcn_s_setprio(0);                                            \
  }

// Conv: grid 32 x 7 = 224 blocks (1/CU). 512 thr = 8 waves, wave = one h-row,
// per-wave tile M=128(o) x N=64(w), 16x16x32 MFMA.
// 4-tap phases: ring of 8 A-slots (2 banks x 4); per phase issue next bank's
// 4 loads AFTER the barrier (overwritten bank provably drained), compute 4
// taps barrier-free (waves drift -> ds_read/MFMA overlap across waves), then
// vmcnt(0)+s_barrier (loads had a full phase in flight -> wait is ~free).
__global__ __launch_bounds__(512, 2) void dcls_conv(
    const unsigned short* __restrict__ xt, const unsigned short* __restrict__ kb,
    const float* __restrict__ bias, float* __restrict__ out)
{
  extern __shared__ char smem[];
  unsigned short* xs = (unsigned short*)smem;            // [ROWS][WP][CCK]
  unsigned short* ab = (unsigned short*)(smem + XS_B);   // ring of 8 [OCH][CCK]

  const int n   = blockIdx.x;
  const int hb  = blockIdx.y;
  const int tid = threadIdx.x;
  const int lane = tid & 63;
  const int wv   = tid >> 6;        // 0..7 = h-row within block
  const int col  = lane & 15;
  const int kgrp = lane >> 4;
  const int swA  = (kgrp ^ ((col >> 1) & 3)) << 3;

  v4f acc[8][4];
  #pragma unroll
  for (int m = 0; m < 8; ++m)
    #pragma unroll
    for (int t = 0; t < 4; ++t)
      acc[m][t] = (v4f){0.f,0.f,0.f,0.f};

  for (int cc = 0; cc < NCC; ++cc) {
    __syncthreads();   // all waves done reading previous cc's xs/ring
    // ---- stage xs: 63 linear KB-lines ----
    const char* src = (const char*)xt + (size_t)((n*NCC + cc)*HP + hb*HBLK)*ROWB;
    for (int i = wv; i < 63; i += 8)
      gl_lds16(src + i*1024 + lane*16, (char*)xs + i*1024);
    // ---- stage phase-0 A tiles (taps 0..3) ----
    const char* ks = (const char*)kb + (size_t)cc*49*8192;
    #pragma unroll
    for (int j = 0; j < 4; ++j)
      gl_lds16(ks + (size_t)j*8192 + wv*1024 + lane*16,
               (char*)ab + (size_t)j*8192 + wv*1024 + lane*16);
    asm volatile("s_waitcnt vmcnt(0)" ::: "memory");
    __builtin_amdgcn_s_barrier();

    #pragma unroll 1
    for (int p = 0; p < 12; ++p) {
      const int tb = 4*p;
      // issue next phase's loads into the other bank (drained by the barrier)
      #pragma unroll
      for (int j = 0; j < 4; ++j) {
        const int T = tb + 4 + j;
        if (T < 49)
          gl_lds16(ks + (size_t)T*8192 + wv*1024 + lane*16,
                   (char*)ab + (size_t)(T & 7)*8192 + wv*1024 + lane*16);
      }
      // compute 4 taps, no barriers between
      TAP_COMPUTE(tb)
      TAP_COMPUTE(tb + 1)
      TAP_COMPUTE(tb + 2)
      TAP_COMPUTE(tb + 3)
      asm volatile("s_waitcnt vmcnt(0)" ::: "memory");
      __builtin_amdgcn_s_barrier();
    }
    TAP_COMPUTE(48)
  }

  // ---- epilogue: D row=(lane>>4)*4+reg, col=lane&15 ----
  const int h = hb*HBLK + wv;
  #pragma unroll
  for (int mt = 0; mt < 8; ++mt) {
    #pragma unroll
    for (int rr = 0; rr < 4; ++rr) {
      const int o = mt*16 + (lane >> 4)*4 + rr;
      const float bs = bias[o];
      #pragma unroll
      for (int nt = 0; nt < 4; ++nt) {
        const int w = nt*16 + col;
        if (w < HW)
          out[((size_t)(n*OCH + o)*HW + h)*HW + w] = acc[mt][nt][rr] + bs;
      }
    }
  }
}

extern "C" void kernel_launch(void* const* d_in, const int* in_sizes, int n_in,
                              void* d_out, int out_size, void* d_ws, size_t ws_size,
                              hipStream_t stream) {
  const float* x    = (const float*)d_in[0];
  const float* wgt  = (const float*)d_in[1];
  const float* P    = (const float*)d_in[2];
  const float* bias = (const float*)d_in[3];
  float* out = (float*)d_out;

  unsigned short* kb = (unsigned short*)d_ws;                       // 1.6 MB
  unsigned short* xt = (unsigned short*)((char*)d_ws + (2u<<20));   // 36.6 MB

  hipFuncSetAttribute((const void*)dcls_conv,
                      hipFuncAttributeMaxDynamicSharedMemorySize, SMEM_B);

  build_kern<<<CCH, OCH, 0, stream>>>(wgt, P, kb);
  xpose<<<dim3(HP, NCC, NB), 256, 0, stream>>>(x, xt);
  dcls_conv<<<dim3(NB, KS), 512, SMEM_B, stream>>>(xt, kb, bias, out);
}